// Round 3
// baseline (129.655 us; speedup 1.0000x reference)
//
#include <hip/hip_runtime.h>

// SelfAttentionPool, fused kernel v7 (round 8).
// History: v4 28.6us kernel (110.6 total) -> v5 33 (115.5) -> v6 30 (114.3).
// Two rounds of shaving intra-block compute moved ~nothing => the ~12us gap
// above the ~18us HBM floor is the grid-wide lockstep phase serialization
// (all 1000 blocks load together, compute together, store together), not any
// single phase's instruction count.
// v7: software pipeline across graphs WITHIN a block: 500 blocks x 2 graphs.
//     Both graphs' global loads issue up front (second register buffer);
//     process(A) runs while B's loads are in flight; process(B) runs while
//     A's stores drain. HBM stays busy under compute. No inter-graph barrier
//     needed (every A-side LDS read is ordered before A's last barrier; every
//     B-side early write is wave-private or behind B's own first barrier).
//     __launch_bounds__(512,4) caps VGPR at 128 -> 2 blocks/CU -> all 500
//     blocks resident. Edge relabel uses register-resident packed edges.
// Numerics: z pipeline stays f64 (selection matches JAX f32 ranking).
//
// Output (float32): x_new (80000*128) | edge0 (E) | edge1 (E) | batch_new (80000)

#define NPG   100
#define EPG   1600
#define KNUM  80
#define FDIM  128
#define BT    512
#define GPB   2
#define NF4   (NPG * FDIM / 4)   // 3200 float4 of x per graph
#define NE4   (EPG / 4)          // 400 int4 per edge row
#define NCH   (NF4 / BT)         // 6 full chunks
#define NREM  (NF4 - NCH * BT)   // 128 remainder float4
#define PSTR  33                 // padded partial stride (doubles)

struct Smem {
    int4   edge4[NE4];              // packed: s | (d<<16)
    int    cnt[8][NPG];             // per-wave private degree
    double part[NPG * PSTR];        // dot partials, padded rows
    double dis[NPG];
    double a[NPG];                  // s * dis
    double zp[8][NPG];              // per-wave private scatter
    double z[NPG];
    unsigned long long mask7[8];
    int    newid[NPG];              // global out row, or -1
    float  scalen[NPG];             // sigmoid(z)
};

__device__ __forceinline__
void process_graph(Smem& sm, int g, int tid, int wave, int lane, float4 th,
                   const float4 (&v)[NCH], float4 vR, int4 es, int4 ed,
                   float* __restrict__ out, int E_total, int out_x_elems)
{
    const int  base = g * NPG;
    const bool hasE = tid < NE4;
    const bool hasR = tid < NREM;
    int* sh_edge = (int*)sm.edge4;

    // per-wave private init -- same-wave ordering, no barrier needed
    {
        int*    cw = sm.cnt[wave];
        double* zw = sm.zp[wave];
        for (int i = lane; i < NPG; i += 64) { cw[i] = 0; zw[i] = 0.0; }
    }

    // ---- edge pack + per-wave degree histogram
    int4 p;
    if (hasE) {
        int4 s4 = es, d4 = ed;
        s4.x -= base; s4.y -= base; s4.z -= base; s4.w -= base;
        d4.x -= base; d4.y -= base; d4.z -= base; d4.w -= base;
        p.x = s4.x | (d4.x << 16); p.y = s4.y | (d4.y << 16);
        p.z = s4.z | (d4.z << 16); p.w = s4.w | (d4.w << 16);
        sm.edge4[tid] = p;
        int* cw = sm.cnt[wave];
        atomicAdd(&cw[s4.x], 1); atomicAdd(&cw[s4.y], 1);
        atomicAdd(&cw[s4.z], 1); atomicAdd(&cw[s4.w], 1);
    }

    // ---- dot: one f64 partial per float4, straight to LDS (no cross-lane)
    #pragma unroll
    for (int i = 0; i < NCH; ++i) {
        int idx = i * BT + tid;
        double dp = (double)v[i].x * th.x + (double)v[i].y * th.y
                  + (double)v[i].z * th.z + (double)v[i].w * th.w;
        sm.part[idx + (idx >> 5)] = dp;
    }
    if (hasR) {
        int idx = NCH * BT + tid;
        double dp = (double)vR.x * th.x + (double)vR.y * th.y
                  + (double)vR.z * th.z + (double)vR.w * th.w;
        sm.part[idx + (idx >> 5)] = dp;
    }
    __syncthreads();                              // B2: edges, cnt, partials

    // ---- reduce: 4 threads/node + 4-lane shfl combine; leader -> dis, a
    if (tid < 4 * NPG) {
        const int n = tid >> 2, q = tid & 3;
        const double* pr = sm.part + n * PSTR + q * 8;
        double s = ((pr[0] + pr[1]) + (pr[2] + pr[3]))
                 + ((pr[4] + pr[5]) + (pr[6] + pr[7]));
        s += __shfl_xor(s, 1, 64);
        s += __shfl_xor(s, 2, 64);
        if (q == 0) {
            int deg = 1 + sm.cnt[0][n] + sm.cnt[1][n] + sm.cnt[2][n]
                        + sm.cnt[3][n] + sm.cnt[4][n] + sm.cnt[5][n]
                        + sm.cnt[6][n] + sm.cnt[7][n];
            double dis = 1.0 / sqrt((double)deg);
            sm.dis[n] = dis;
            sm.a[n]   = s * dis;
        }
    }
    __syncthreads();                              // B3: dis/a ready

    // ---- z scatter: accumulate sum of a[s] per dst (dis[d] hoisted)
    {
        double* zw = sm.zp[wave];
        for (int j = tid; j < EPG; j += BT) {
            int e = sh_edge[j];
            atomicAdd(&zw[e >> 16], sm.a[e & 0xffff]);
        }
    }
    __syncthreads();                              // B4: scatter done

    if (tid < NPG) {
        double zi = sm.a[tid]                     // self-loop term
                  + sm.zp[0][tid] + sm.zp[1][tid] + sm.zp[2][tid] + sm.zp[3][tid]
                  + sm.zp[4][tid] + sm.zp[5][tid] + sm.zp[6][tid] + sm.zp[7][tid];
        sm.z[tid] = zi * sm.dis[tid];
        sm.newid[tid] = -1;
    }
    __syncthreads();                              // B5: z ready

    // ---- top-k rank, 4 threads/node (25 scans each) + shfl combine
    const bool rk = tid < 4 * NPG;
    const int  n2 = tid >> 2;
    int r = 0;
    double zn = 0.0;
    if (rk) {
        zn = sm.z[n2];
        const int j0 = (tid & 3) * 25;
        for (int j = j0; j < j0 + 25; ++j) {
            double zj = sm.z[j];
            r += (int)((zj > zn) | ((zj == zn) & (j < n2)));
        }
    }
    r += __shfl_xor(r, 1, 64);
    r += __shfl_xor(r, 2, 64);
    const bool lead = rk && ((tid & 3) == 0) && (r < KNUM);
    unsigned long long m = __ballot(lead);
    if (lane == 0) sm.mask7[wave] = m;
    __syncthreads();                              // B6a: masks ready

    if (lead) {
        int before = __popcll(m & ((1ull << lane) - 1ull));
        for (int w2 = 0; w2 < wave; ++w2) before += __popcll(sm.mask7[w2]);
        int row = g * KNUM + before;
        sm.newid[n2]  = row;
        sm.scalen[n2] = 1.0f / (1.0f + __expf(-(float)zn));
        out[(size_t)out_x_elems + 2 * (size_t)E_total + row] = (float)g; // batch_new
    }
    __syncthreads();                              // B6: newid/scalen ready

    // ---- x_new straight from the register-resident tile
    float4* outx = (float4*)out;
    #pragma unroll
    for (int i = 0; i < NCH; ++i) {
        int idx = i * BT + tid;
        int nid = sm.newid[idx >> 5];
        if (nid >= 0) {
            float sc = sm.scalen[idx >> 5];
            float4 o;
            o.x = v[i].x * sc; o.y = v[i].y * sc;
            o.z = v[i].z * sc; o.w = v[i].w * sc;
            outx[(size_t)nid * 32 + (idx & 31)] = o;
        }
    }
    if (hasR) {
        int idx = NCH * BT + tid;
        int nid = sm.newid[idx >> 5];
        if (nid >= 0) {
            float sc = sm.scalen[idx >> 5];
            float4 o;
            o.x = vR.x * sc; o.y = vR.y * sc;
            o.z = vR.z * sc; o.w = vR.w * sc;
            outx[(size_t)nid * 32 + (idx & 31)] = o;
        }
    }

    // ---- edge relabel from register-resident packed edges
    float* e0 = out + out_x_elems;
    float* e1 = e0 + E_total;
    if (hasE) {
        float4 o0, o1;
        {
            int a_ = sm.newid[p.x & 0xffff], b_ = sm.newid[p.x >> 16];
            bool vv = (a_ >= 0) && (b_ >= 0);
            o0.x = vv ? (float)a_ : -1.0f; o1.x = vv ? (float)b_ : -1.0f;
        }
        {
            int a_ = sm.newid[p.y & 0xffff], b_ = sm.newid[p.y >> 16];
            bool vv = (a_ >= 0) && (b_ >= 0);
            o0.y = vv ? (float)a_ : -1.0f; o1.y = vv ? (float)b_ : -1.0f;
        }
        {
            int a_ = sm.newid[p.z & 0xffff], b_ = sm.newid[p.z >> 16];
            bool vv = (a_ >= 0) && (b_ >= 0);
            o0.z = vv ? (float)a_ : -1.0f; o1.z = vv ? (float)b_ : -1.0f;
        }
        {
            int a_ = sm.newid[p.w & 0xffff], b_ = sm.newid[p.w >> 16];
            bool vv = (a_ >= 0) && (b_ >= 0);
            o0.w = vv ? (float)a_ : -1.0f; o1.w = vv ? (float)b_ : -1.0f;
        }
        ((float4*)e0)[(size_t)g * NE4 + tid] = o0;
        ((float4*)e1)[(size_t)g * NE4 + tid] = o1;
    }
}

__global__ __launch_bounds__(BT, 4)
void sagpool_fused7(const float* __restrict__ x,
                    const int*   __restrict__ ei,
                    const float* __restrict__ theta,
                    float* __restrict__ out,
                    int E_total, int out_x_elems, int n_graphs)
{
    __shared__ Smem sm;
    const int tid  = threadIdx.x;
    const int wave = tid >> 6;
    const int lane = tid & 63;
    const int gA   = blockIdx.x * GPB;
    const int gB   = gA + 1;
    const bool hasE = tid < NE4;
    const bool hasR = tid < NREM;

    const float4 th = ((const float4*)theta)[lane & 31];

    // ---- issue ALL of graph A's loads, then ALL of graph B's loads.
    // Both streams in flight; process(A) overlaps B's memory latency.
    int4 esA, edA, esB, edB;
    float4 vA[NCH], vB[NCH], vRA, vRB;

    if (hasE) {
        esA = ((const int4*)(ei + (size_t)gA * EPG))[tid];
        edA = ((const int4*)(ei + (size_t)E_total + (size_t)gA * EPG))[tid];
    }
    {
        const float4* xb4 = (const float4*)(x + (size_t)gA * NPG * FDIM);
        #pragma unroll
        for (int i = 0; i < NCH; ++i) vA[i] = xb4[i * BT + tid];
        if (hasR) vRA = xb4[NCH * BT + tid];
    }
    const bool doB = gB < n_graphs;
    if (doB) {
        if (hasE) {
            esB = ((const int4*)(ei + (size_t)gB * EPG))[tid];
            edB = ((const int4*)(ei + (size_t)E_total + (size_t)gB * EPG))[tid];
        }
        const float4* xb4 = (const float4*)(x + (size_t)gB * NPG * FDIM);
        #pragma unroll
        for (int i = 0; i < NCH; ++i) vB[i] = xb4[i * BT + tid];
        if (hasR) vRB = xb4[NCH * BT + tid];
    }

    process_graph(sm, gA, tid, wave, lane, th, vA, vRA, esA, edA,
                  out, E_total, out_x_elems);
    // no inter-graph barrier needed: all A-side LDS reads are ordered before
    // A's last barrier; B's early writes are wave-private (cnt/zp) or target
    // buffers whose A-reads completed before barriers each wave has passed.
    if (doB)
        process_graph(sm, gB, tid, wave, lane, th, vB, vRB, esB, edB,
                      out, E_total, out_x_elems);
}

extern "C" void kernel_launch(void* const* d_in, const int* in_sizes, int n_in,
                              void* d_out, int out_size, void* d_ws, size_t ws_size,
                              hipStream_t stream)
{
    const float* x     = (const float*)d_in[0];
    const int*   ei    = (const int*)d_in[1];
    const float* theta = (const float*)d_in[3];
    float* out = (float*)d_out;

    const int N = in_sizes[0] / FDIM;        // 100000
    const int E = in_sizes[1] / 2;           // 1600000
    const int B = N / NPG;                   // 1000
    const int out_x_elems = B * KNUM * FDIM; // 10,240,000
    const int nb = (B + GPB - 1) / GPB;      // 500 blocks

    sagpool_fused7<<<dim3(nb), dim3(BT), 0, stream>>>(x, ei, theta, out,
                                                      E, out_x_elems, B);
}

// Round 4
// 112.529 us; speedup vs baseline: 1.1522x; 1.1522x over previous
//
#include <hip/hip_runtime.h>

// SelfAttentionPool, fused kernel v8 (round 9).
// History: v4 28.6us kernel (110.6 total) -> v5/v6 ~30-33 (intra-block compute
// shaving: no effect) -> v7 43.5 (GPB=2 via register double-buffer: SPILLED,
// WRITE_SIZE 88.7MB = +128B/thread scratch traffic, occupancy 26%).
// v8: GPB=2 kept, but graph B's x staged via __builtin_amdgcn_global_load_lds
//     into a 51.2KB LDS buffer (zero VGPR cost -> no spill). B's loads are
//     issued AFTER A's dot consumed A's x (requests queue behind A's ->
//     grid-wide stagger). All intra-graph barriers are raw s_barrier +
//     s_waitcnt lgkmcnt(0) (NO vmcnt drain) so the prefetch stays in flight
//     across A's phases; one full __syncthreads() at B-start guarantees xB
//     landed. part[] shrunk 26.4->7.2KB (two shfl_xor folds pre-write) to fit
//     2 blocks/CU at ~77.7KB LDS. 500 blocks x 16 waves/CU: all resident.
// Numerics: z pipeline stays f64 (selection matches JAX f32 ranking).
//
// Output (float32): x_new (80000*128) | edge0 (E) | edge1 (E) | batch_new (80000)

#define NPG   100
#define EPG   1600
#define KNUM  80
#define FDIM  128
#define BT    512
#define NF4   (NPG * FDIM / 4)   // 3200 float4 of x per graph
#define NE4   (EPG / 4)          // 400 int4 per edge row
#define NCH   (NF4 / BT)         // 6 full chunks
#define NREM  (NF4 - NCH * BT)   // 128 remainder float4
#define P8    9                  // padded partial row stride (doubles)

struct Smem {
    alignas(16) float xB[NPG * FDIM];   // 51200B: staged x for graph B
    int4   edge4[NE4];                  // 6400B  packed: s | (d<<16)
    int    cnt[8][NPG];                 // 3200B  per-wave private degree
    double part[NPG * P8];              // 7200B  dot partials (8/node, padded)
    double dis[NPG];                    // 800B
    double a[NPG];                      // 800B   s * dis
    double zp[8][NPG];                  // 6400B  per-wave private scatter
    double z[NPG];                      // 800B
    unsigned long long mask7[8];        // 64B
    int    newid[NPG];                  // 400B
    float  scalen[NPG];                 // 400B
};                                      // ~77.7KB -> 2 blocks/CU

typedef __attribute__((address_space(1))) const unsigned int gu32;
typedef __attribute__((address_space(3))) unsigned int lu32;

// Barrier WITHOUT vmcnt drain: LDS producer/consumer ordering only.
// (__syncthreads would emit s_waitcnt vmcnt(0) and drain the B-prefetch.)
__device__ __forceinline__ void bar_nodrain() {
    asm volatile("s_waitcnt lgkmcnt(0)" ::: "memory");
    __builtin_amdgcn_s_barrier();
    asm volatile("" ::: "memory");
}

template<bool FROMLDS, bool PF>
__device__ __forceinline__
void process_graph(Smem& sm, int g, int tid, int wave, int lane, float4 th,
                   float4 (&v)[NCH], float4& vR, int4 es, int4 ed,
                   const float4* pfsrc,
                   float* __restrict__ out, int E_total, int out_x_elems)
{
    const int  base = g * NPG;
    const bool hasE = tid < NE4;
    const bool hasR = tid < NREM;
    int* sh_edge = (int*)sm.edge4;

    // per-wave private init -- same-wave LDS ordering, no barrier needed
    {
        int*    cw = sm.cnt[wave];
        double* zw = sm.zp[wave];
        for (int i = lane; i < NPG; i += 64) { cw[i] = 0; zw[i] = 0.0; }
    }

    // ---- edge pack + per-wave degree histogram
    int4 p;
    if (hasE) {
        int4 s4 = es, d4 = ed;
        s4.x -= base; s4.y -= base; s4.z -= base; s4.w -= base;
        d4.x -= base; d4.y -= base; d4.z -= base; d4.w -= base;
        p.x = s4.x | (d4.x << 16); p.y = s4.y | (d4.y << 16);
        p.z = s4.z | (d4.z << 16); p.w = s4.w | (d4.w << 16);
        sm.edge4[tid] = p;
        int* cw = sm.cnt[wave];
        atomicAdd(&cw[s4.x], 1); atomicAdd(&cw[s4.y], 1);
        atomicAdd(&cw[s4.z], 1); atomicAdd(&cw[s4.w], 1);
    }

    // ---- dot: f64 partial, 2 shfl_xor folds (4 lanes -> 1), 8 partials/node
    const float4* xl = (const float4*)sm.xB;
    #pragma unroll
    for (int i = 0; i < NCH; ++i) {
        int idx = i * BT + tid;
        if (FROMLDS) v[i] = xl[idx];
        double dp = (double)v[i].x * th.x + (double)v[i].y * th.y
                  + (double)v[i].z * th.z + (double)v[i].w * th.w;
        dp += __shfl_xor(dp, 1, 64);
        dp += __shfl_xor(dp, 2, 64);
        if ((lane & 3) == 0)
            sm.part[(idx >> 5) * P8 + ((idx & 31) >> 2)] = dp;
    }
    if (hasR) {                                   // waves 0,1 only (uniform)
        int idx = NCH * BT + tid;
        if (FROMLDS) vR = xl[idx];
        double dp = (double)vR.x * th.x + (double)vR.y * th.y
                  + (double)vR.z * th.z + (double)vR.w * th.w;
        dp += __shfl_xor(dp, 1, 64);
        dp += __shfl_xor(dp, 2, 64);
        if ((lane & 3) == 0)
            sm.part[(idx >> 5) * P8 + ((idx & 31) >> 2)] = dp;
    }

    if (PF) {
        // async-stage NEXT graph's x into sm.xB. Issued only now (this
        // graph's x already consumed) so these requests queue behind the
        // grid's first-wave loads. LDS dest = wave-uniform base + lane*16.
        #pragma unroll
        for (int i = 0; i < NCH; ++i) {
            int idx = i * BT + tid;
            __builtin_amdgcn_global_load_lds((gu32*)(pfsrc + idx),
                (lu32*)(sm.xB + (size_t)(i * BT + wave * 64) * 4), 16, 0, 0);
        }
        if (wave < 2) {
            int idx = NCH * BT + tid;
            __builtin_amdgcn_global_load_lds((gu32*)(pfsrc + idx),
                (lu32*)(sm.xB + (size_t)(NCH * BT + wave * 64) * 4), 16, 0, 0);
        }
    }
    bar_nodrain();                                // B2: edges, cnt, partials

    // ---- reduce: 1 thread/node sums 8 partials; folds deg -> dis, a
    if (tid < NPG) {
        const double* pr = sm.part + tid * P8;
        double s = ((pr[0] + pr[1]) + (pr[2] + pr[3]))
                 + ((pr[4] + pr[5]) + (pr[6] + pr[7]));
        int deg = 1 + sm.cnt[0][tid] + sm.cnt[1][tid] + sm.cnt[2][tid]
                    + sm.cnt[3][tid] + sm.cnt[4][tid] + sm.cnt[5][tid]
                    + sm.cnt[6][tid] + sm.cnt[7][tid];
        double dis = 1.0 / sqrt((double)deg);
        sm.dis[tid] = dis;
        sm.a[tid]   = s * dis;
    }
    bar_nodrain();                                // B3: dis/a ready

    // ---- z scatter: accumulate sum of a[s] per dst (dis[d] hoisted)
    {
        double* zw = sm.zp[wave];
        for (int j = tid; j < EPG; j += BT) {
            int e = sh_edge[j];
            atomicAdd(&zw[e >> 16], sm.a[e & 0xffff]);
        }
    }
    bar_nodrain();                                // B4: scatter done

    if (tid < NPG) {
        double zi = sm.a[tid]                     // self-loop term
                  + sm.zp[0][tid] + sm.zp[1][tid] + sm.zp[2][tid] + sm.zp[3][tid]
                  + sm.zp[4][tid] + sm.zp[5][tid] + sm.zp[6][tid] + sm.zp[7][tid];
        sm.z[tid] = zi * sm.dis[tid];
        sm.newid[tid] = -1;
    }
    bar_nodrain();                                // B5: z ready

    // ---- top-k rank, 4 threads/node (25 scans each) + shfl combine
    const bool rk = tid < 4 * NPG;
    const int  n2 = tid >> 2;
    int r = 0;
    double zn = 0.0;
    if (rk) {
        zn = sm.z[n2];
        const int j0 = (tid & 3) * 25;
        for (int j = j0; j < j0 + 25; ++j) {
            double zj = sm.z[j];
            r += (int)((zj > zn) | ((zj == zn) & (j < n2)));
        }
    }
    r += __shfl_xor(r, 1, 64);
    r += __shfl_xor(r, 2, 64);
    const bool lead = rk && ((tid & 3) == 0) && (r < KNUM);
    unsigned long long m = __ballot(lead);
    if (lane == 0) sm.mask7[wave] = m;
    bar_nodrain();                                // B6a: masks ready

    if (lead) {
        int before = __popcll(m & ((1ull << lane) - 1ull));
        for (int w2 = 0; w2 < wave; ++w2) before += __popcll(sm.mask7[w2]);
        int row = g * KNUM + before;
        sm.newid[n2]  = row;
        sm.scalen[n2] = 1.0f / (1.0f + __expf(-(float)zn));
        out[(size_t)out_x_elems + 2 * (size_t)E_total + row] = (float)g; // batch_new
    }
    bar_nodrain();                                // B6: newid/scalen ready

    // ---- x_new from the register-resident tile (filled from LDS if B)
    float4* outx = (float4*)out;
    #pragma unroll
    for (int i = 0; i < NCH; ++i) {
        int idx = i * BT + tid;
        int nid = sm.newid[idx >> 5];
        if (nid >= 0) {
            float sc = sm.scalen[idx >> 5];
            float4 o;
            o.x = v[i].x * sc; o.y = v[i].y * sc;
            o.z = v[i].z * sc; o.w = v[i].w * sc;
            outx[(size_t)nid * 32 + (idx & 31)] = o;
        }
    }
    if (hasR) {
        int idx = NCH * BT + tid;
        int nid = sm.newid[idx >> 5];
        if (nid >= 0) {
            float sc = sm.scalen[idx >> 5];
            float4 o;
            o.x = vR.x * sc; o.y = vR.y * sc;
            o.z = vR.z * sc; o.w = vR.w * sc;
            outx[(size_t)nid * 32 + (idx & 31)] = o;
        }
    }

    // ---- edge relabel from register-resident packed edges
    float* e0 = out + out_x_elems;
    float* e1 = e0 + E_total;
    if (hasE) {
        float4 o0, o1;
        {
            int a_ = sm.newid[p.x & 0xffff], b_ = sm.newid[p.x >> 16];
            bool vv = (a_ >= 0) && (b_ >= 0);
            o0.x = vv ? (float)a_ : -1.0f; o1.x = vv ? (float)b_ : -1.0f;
        }
        {
            int a_ = sm.newid[p.y & 0xffff], b_ = sm.newid[p.y >> 16];
            bool vv = (a_ >= 0) && (b_ >= 0);
            o0.y = vv ? (float)a_ : -1.0f; o1.y = vv ? (float)b_ : -1.0f;
        }
        {
            int a_ = sm.newid[p.z & 0xffff], b_ = sm.newid[p.z >> 16];
            bool vv = (a_ >= 0) && (b_ >= 0);
            o0.z = vv ? (float)a_ : -1.0f; o1.z = vv ? (float)b_ : -1.0f;
        }
        {
            int a_ = sm.newid[p.w & 0xffff], b_ = sm.newid[p.w >> 16];
            bool vv = (a_ >= 0) && (b_ >= 0);
            o0.w = vv ? (float)a_ : -1.0f; o1.w = vv ? (float)b_ : -1.0f;
        }
        ((float4*)e0)[(size_t)g * NE4 + tid] = o0;
        ((float4*)e1)[(size_t)g * NE4 + tid] = o1;
    }
}

__global__ __launch_bounds__(BT, 4)
void sagpool_fused8(const float* __restrict__ x,
                    const int*   __restrict__ ei,
                    const float* __restrict__ theta,
                    float* __restrict__ out,
                    int E_total, int out_x_elems, int n_graphs)
{
    __shared__ Smem sm;
    const int tid  = threadIdx.x;
    const int wave = tid >> 6;
    const int lane = tid & 63;
    const int gA   = blockIdx.x * 2;
    const int gB   = gA + 1;
    const bool hasE = tid < NE4;
    const bool hasR = tid < NREM;
    const bool doB  = gB < n_graphs;

    const float4 th = ((const float4*)theta)[lane & 31];

    // t0 loads: A edges + B edges (small) + A x-tile into registers.
    int4 esA = {0,0,0,0}, edA = {0,0,0,0}, esB = {0,0,0,0}, edB = {0,0,0,0};
    if (hasE) {
        esA = ((const int4*)(ei + (size_t)gA * EPG))[tid];
        edA = ((const int4*)(ei + (size_t)E_total + (size_t)gA * EPG))[tid];
        if (doB) {
            esB = ((const int4*)(ei + (size_t)gB * EPG))[tid];
            edB = ((const int4*)(ei + (size_t)E_total + (size_t)gB * EPG))[tid];
        }
    }
    float4 v[NCH];
    float4 vR = {0.f, 0.f, 0.f, 0.f};
    const float4* xA = (const float4*)(x + (size_t)gA * NPG * FDIM);
    const float4* xB = (const float4*)(x + (size_t)gB * NPG * FDIM);
    #pragma unroll
    for (int i = 0; i < NCH; ++i) v[i] = xA[i * BT + tid];
    if (hasR) vR = xA[NCH * BT + tid];

    process_graph<false, true>(sm, gA, tid, wave, lane, th, v, vR, esA, edA,
                               xB, out, E_total, out_x_elems);
    if (doB) {
        // Full drain: guarantees the async-staged xB landed in LDS, all of
        // A's LDS reads are complete, and A's stores are retired.
        __syncthreads();
        process_graph<true, false>(sm, gB, tid, wave, lane, th, v, vR, esB, edB,
                                   nullptr, out, E_total, out_x_elems);
    }
}

extern "C" void kernel_launch(void* const* d_in, const int* in_sizes, int n_in,
                              void* d_out, int out_size, void* d_ws, size_t ws_size,
                              hipStream_t stream)
{
    const float* x     = (const float*)d_in[0];
    const int*   ei    = (const int*)d_in[1];
    const float* theta = (const float*)d_in[3];
    float* out = (float*)d_out;

    const int N = in_sizes[0] / FDIM;        // 100000
    const int E = in_sizes[1] / 2;           // 1600000
    const int B = N / NPG;                   // 1000
    const int out_x_elems = B * KNUM * FDIM; // 10,240,000
    const int nb = (B + 1) / 2;              // 500 blocks

    sagpool_fused8<<<dim3(nb), dim3(BT), 0, stream>>>(x, ei, theta, out,
                                                      E, out_x_elems, B);
}